// Round 1
// baseline (414.877 us; speedup 1.0000x reference)
//
#include <hip/hip_runtime.h>

#define SEQ 2048
#define DIM 1024
#define NH 16
#define HDIM 64
#define PFF 4096
#define NROWS 4096  // B*S
#define BATCH 2

typedef unsigned short u16;
typedef unsigned int u32;
typedef __attribute__((ext_vector_type(8))) short short8;
typedef __attribute__((ext_vector_type(4))) float f32x4;

__device__ inline float b2f(u16 u){ return __uint_as_float(((u32)u)<<16); }
__device__ inline u16 f2b(float f){
  u32 u = __float_as_uint(f);
  u32 r = u + 0x7FFFu + ((u>>16)&1u);
  return (u16)(r>>16);
}

// ---------------- elementwise cast fp32 -> bf16 (float4 per thread) ----------------
__global__ void k_cast_bf16(const float* __restrict__ in, u16* __restrict__ out, int n4){
  int i = blockIdx.x*256 + threadIdx.x;
  if (i >= n4) return;
  float4 v = ((const float4*)in)[i];
  ushort4 o;
  o.x = f2b(v.x); o.y = f2b(v.y); o.z = f2b(v.z); o.w = f2b(v.w);
  ((ushort4*)out)[i] = o;
}

// ---------------- transpose + cast: in fp32 [R][C] -> out bf16 [C][R] ----------------
__global__ __launch_bounds__(256) void k_transpose_cast(const float* __restrict__ in,
                                                        u16* __restrict__ out, int R, int C){
  __shared__ float tile[32][33];
  int tx = threadIdx.x & 31, ty = threadIdx.x >> 5;
  int c0 = blockIdx.x*32, r0 = blockIdx.y*32;
  #pragma unroll
  for (int i=0;i<4;++i)
    tile[ty+i*8][tx] = in[(size_t)(r0+ty+i*8)*C + c0 + tx];
  __syncthreads();
  #pragma unroll
  for (int i=0;i<4;++i)
    out[(size_t)(c0+ty+i*8)*R + r0 + tx] = f2b(tile[tx][ty+i*8]);
}

// ---------------- GEMM: C[M][N] = A[M][K](bf16) * Bt[N][K](bf16)^T + bias ----------------
template<bool RELU, bool BF16OUT>
__global__ __launch_bounds__(256) void k_gemm(
    const u16* __restrict__ A, const u16* __restrict__ Bt,
    const float* __restrict__ bias, void* __restrict__ Cp,
    int M, int N, int K){
  __shared__ __align__(16) char lds[32768];
  const int tid = threadIdx.x;
  const int lane = tid & 63, wid = tid >> 6;
  const int quad = lane >> 4, l15 = lane & 15;
  const int wr = wid >> 1, wc = wid & 1;
  const int rowBase = blockIdx.y * 128, colBase = blockIdx.x * 128;
  f32x4 acc[4][4] = {};
  for (int k0 = 0; k0 < K; k0 += 64) {
    __syncthreads();
    #pragma unroll
    for (int i=0;i<4;++i){
      int chunk = tid + i*256;
      int row = chunk >> 3, c8 = chunk & 7;
      uint4 va = *(const uint4*)(A + (size_t)(rowBase+row)*K + k0 + c8*8);
      *(uint4*)(lds + ((row*128 + c8*16) ^ ((row&7)<<4))) = va;
      uint4 vb = *(const uint4*)(Bt + (size_t)(colBase+row)*K + k0 + c8*8);
      *(uint4*)(lds + 16384 + ((row*128 + c8*16) ^ ((row&7)<<4))) = vb;
    }
    __syncthreads();
    #pragma unroll
    for (int kk=0;kk<2;++kk){
      short8 af[4], bfr[4];
      #pragma unroll
      for (int m=0;m<4;++m){
        int r = wr*64 + m*16 + l15;
        af[m] = *(const short8*)(lds + ((r*128 + kk*64 + quad*16) ^ ((r&7)<<4)));
      }
      #pragma unroll
      for (int n=0;n<4;++n){
        int r = wc*64 + n*16 + l15;
        bfr[n] = *(const short8*)(lds + 16384 + ((r*128 + kk*64 + quad*16) ^ ((r&7)<<4)));
      }
      #pragma unroll
      for (int m=0;m<4;++m)
        #pragma unroll
        for (int n=0;n<4;++n)
          acc[m][n] = __builtin_amdgcn_mfma_f32_16x16x32_bf16(af[m], bfr[n], acc[m][n], 0,0,0);
    }
  }
  #pragma unroll
  for (int m=0;m<4;++m){
    #pragma unroll
    for (int n=0;n<4;++n){
      int col = colBase + wc*64 + n*16 + l15;
      float bv = bias[col];
      #pragma unroll
      for (int j=0;j<4;++j){
        int row = rowBase + wr*64 + m*16 + quad*4 + j;
        float v = acc[m][n][j] + bv;
        if (RELU) v = fmaxf(v, 0.f);
        if (BF16OUT) ((u16*)Cp)[(size_t)row*N + col] = f2b(v);
        else         ((float*)Cp)[(size_t)row*N + col] = v;
      }
    }
  }
}

// ---------------- RoPE in-place on bf16 Q (scaled by 1/8) and K ----------------
__global__ void k_rope(u16* __restrict__ Qb, u16* __restrict__ Kb,
                       const float* __restrict__ cosT, const float* __restrict__ sinT){
  int idx = blockIdx.x*256 + threadIdx.x;   // NROWS*512 threads, one pair each
  int row = idx >> 9, p = idx & 511;
  int s = row & (SEQ-1);
  float c = cosT[s*512 + p], sn = sinT[s*512 + p];
  ushort2 q = ((const ushort2*)Qb)[idx];
  ushort2 k = ((const ushort2*)Kb)[idx];
  float qx = b2f(q.x), qy = b2f(q.y), kx = b2f(k.x), ky = b2f(k.y);
  const float scale = 0.125f;   // 1/sqrt(HD)
  ushort2 qo, ko;
  qo.x = f2b((qx*c - qy*sn)*scale);
  qo.y = f2b((qx*sn + qy*c)*scale);
  ko.x = f2b(kx*c - ky*sn);
  ko.y = f2b(kx*sn + ky*c);
  ((ushort2*)Qb)[idx] = qo;
  ((ushort2*)Kb)[idx] = ko;
}

// ---------------- flash attention: block = (q-tile 64, head, batch), 4 waves ----------------
__global__ __launch_bounds__(256) void k_attn(
    const u16* __restrict__ Qb, const u16* __restrict__ Kb,
    const u16* __restrict__ Vb, u16* __restrict__ Xo){
  const int qt = blockIdx.x, h = blockIdx.y, b = blockIdx.z;
  const int tid = threadIdx.x, lane = tid & 63, wid = tid >> 6;
  const int quad = lane >> 4, l15 = lane & 15;
  __shared__ __align__(16) char lds[32768];
  // regions: Q [64][64] @0, K [64][64] @8192, Vt [64][64] @16384, P per-wave [16][64] @24576+wid*2048
  const size_t baseQ = ((size_t)(b*SEQ + qt*64))*DIM + h*HDIM;
  #pragma unroll
  for (int i=0;i<2;++i){
    int chunk = tid + i*256, row = chunk>>3, c8 = chunk&7;
    uint4 v = *(const uint4*)(Qb + baseQ + (size_t)row*DIM + c8*8);
    *(uint4*)(lds + ((row*128 + c8*16) ^ ((row&7)<<4))) = v;
  }
  float m_run[4] = {-1e30f,-1e30f,-1e30f,-1e30f};
  float s_run[4] = {0.f,0.f,0.f,0.f};
  f32x4 oacc[4] = {};
  for (int kt=0; kt<SEQ/64; ++kt){
    __syncthreads();
    const size_t baseK = ((size_t)(b*SEQ + kt*64))*DIM + h*HDIM;
    #pragma unroll
    for (int i=0;i<2;++i){
      int chunk = tid + i*256, row = chunk>>3, c8 = chunk&7;
      uint4 v = *(const uint4*)(Kb + baseK + (size_t)row*DIM + c8*8);
      *(uint4*)(lds + 8192 + ((row*128 + c8*16) ^ ((row&7)<<4))) = v;
    }
    { // V staged transposed: Vt[hd][krow]
      int krow = tid >> 2, hd0 = (tid & 3)*16;
      const u16* vp = Vb + baseK + (size_t)krow*DIM + hd0;
      uint4 v0 = *(const uint4*)vp;
      uint4 v1 = *(const uint4*)(vp + 8);
      union { uint4 v[2]; u16 u[16]; } tmp;
      tmp.v[0] = v0; tmp.v[1] = v1;
      #pragma unroll
      for (int e=0;e<16;++e){
        int hd = hd0 + e;
        *(u16*)(lds + 16384 + ((hd*128 + krow*2) ^ ((hd&7)<<4))) = tmp.u[e];
      }
    }
    __syncthreads();
    // S = Q*K^T for this wave's 16 q-rows
    f32x4 sacc[4] = {};
    #pragma unroll
    for (int kk=0;kk<2;++kk){
      int ar = wid*16 + l15;
      short8 a = *(const short8*)(lds + ((ar*128 + kk*64 + quad*16) ^ ((ar&7)<<4)));
      #pragma unroll
      for (int n=0;n<4;++n){
        int br = n*16 + l15;
        short8 bb = *(const short8*)(lds + 8192 + ((br*128 + kk*64 + quad*16) ^ ((br&7)<<4)));
        sacc[n] = __builtin_amdgcn_mfma_f32_16x16x32_bf16(a, bb, sacc[n], 0,0,0);
      }
    }
    // online softmax (rows = quad*4+j, cols across 16 lanes x 4 n-blocks)
    float mnew[4], alpha[4], tsum[4];
    #pragma unroll
    for (int j=0;j<4;++j){
      float t = fmaxf(fmaxf(sacc[0][j], sacc[1][j]), fmaxf(sacc[2][j], sacc[3][j]));
      #pragma unroll
      for (int mm=8;mm>=1;mm>>=1) t = fmaxf(t, __shfl_xor(t, mm));
      mnew[j] = fmaxf(m_run[j], t);
      alpha[j] = __expf(m_run[j] - mnew[j]);
      tsum[j] = 0.f;
    }
    u16 pb[4][4];
    #pragma unroll
    for (int n=0;n<4;++n){
      #pragma unroll
      for (int j=0;j<4;++j){
        float p = __expf(sacc[n][j] - mnew[j]);
        tsum[j] += p;
        pb[n][j] = f2b(p);
      }
    }
    #pragma unroll
    for (int j=0;j<4;++j){
      float t = tsum[j];
      #pragma unroll
      for (int mm=8;mm>=1;mm>>=1) t += __shfl_xor(t, mm);
      s_run[j] = s_run[j]*alpha[j] + t;
      m_run[j] = mnew[j];
    }
    #pragma unroll
    for (int nb=0;nb<4;++nb){
      #pragma unroll
      for (int j=0;j<4;++j) oacc[nb][j] *= alpha[j];
    }
    // write P (bf16) to this wave's LDS region
    #pragma unroll
    for (int n=0;n<4;++n){
      #pragma unroll
      for (int j=0;j<4;++j){
        int pr = quad*4 + j, pc = n*16 + l15;
        *(u16*)(lds + 24576 + wid*2048 + ((pr*128 + pc*2) ^ ((pr&7)<<4))) = pb[n][j];
      }
    }
    __syncthreads();
    // O += P * V
    #pragma unroll
    for (int kk=0;kk<2;++kk){
      int ar = l15;
      short8 a = *(const short8*)(lds + 24576 + wid*2048 + ((ar*128 + kk*64 + quad*16) ^ ((ar&7)<<4)));
      #pragma unroll
      for (int nb=0;nb<4;++nb){
        int br = nb*16 + l15;
        short8 bb = *(const short8*)(lds + 16384 + ((br*128 + kk*64 + quad*16) ^ ((br&7)<<4)));
        oacc[nb] = __builtin_amdgcn_mfma_f32_16x16x32_bf16(a, bb, oacc[nb], 0,0,0);
      }
    }
  }
  #pragma unroll
  for (int nb=0;nb<4;++nb){
    #pragma unroll
    for (int j=0;j<4;++j){
      int row = qt*64 + wid*16 + quad*4 + j;
      int col = h*HDIM + nb*16 + l15;
      float v = oacc[nb][j] / s_run[j];
      Xo[((size_t)(b*SEQ + row))*DIM + col] = f2b(v);
    }
  }
}

// ---------------- residual + layernorm (row per block), optional bf16 copy ----------------
template<bool WBF>
__global__ __launch_bounds__(256) void k_ln(
    const float* __restrict__ a, const float* __restrict__ b,
    const float* __restrict__ g, const float* __restrict__ be,
    float* __restrict__ outf, u16* __restrict__ outb){
  const int row = blockIdx.x, tid = threadIdx.x;
  __shared__ float red[8];
  float4 av = ((const float4*)(a + (size_t)row*DIM))[tid];
  float4 bv = ((const float4*)(b + (size_t)row*DIM))[tid];
  float x0 = av.x+bv.x, x1 = av.y+bv.y, x2 = av.z+bv.z, x3 = av.w+bv.w;
  float s = x0+x1+x2+x3;
  #pragma unroll
  for (int o=32;o>=1;o>>=1) s += __shfl_down(s, o);
  if ((tid&63)==0) red[tid>>6] = s;
  __syncthreads();
  float mean = (red[0]+red[1]+red[2]+red[3]) * (1.0f/DIM);
  float d0=x0-mean, d1=x1-mean, d2=x2-mean, d3=x3-mean;
  float vs = d0*d0+d1*d1+d2*d2+d3*d3;
  #pragma unroll
  for (int o=32;o>=1;o>>=1) vs += __shfl_down(vs, o);
  if ((tid&63)==0) red[4+(tid>>6)] = vs;
  __syncthreads();
  float var = (red[4]+red[5]+red[6]+red[7]) * (1.0f/DIM);
  float rs = rsqrtf(var + 1e-5f);
  float4 gv = ((const float4*)g)[tid];
  float4 bev = ((const float4*)be)[tid];
  float4 y;
  y.x = d0*rs*gv.x + bev.x;
  y.y = d1*rs*gv.y + bev.y;
  y.z = d2*rs*gv.z + bev.z;
  y.w = d3*rs*gv.w + bev.w;
  ((float4*)(outf + (size_t)row*DIM))[tid] = y;
  if (WBF){
    ushort4 o4; o4.x=f2b(y.x); o4.y=f2b(y.y); o4.z=f2b(y.z); o4.w=f2b(y.w);
    ((ushort4*)(outb + (size_t)row*DIM))[tid] = o4;
  }
}

extern "C" void kernel_launch(void* const* d_in, const int* in_sizes, int n_in,
                              void* d_out, int out_size, void* d_ws, size_t ws_size,
                              hipStream_t stream){
  (void)in_sizes; (void)n_in; (void)out_size; (void)ws_size;
  const float* src  = (const float*)d_in[0];
  const float* Wq   = (const float*)d_in[1];
  const float* bq   = (const float*)d_in[2];
  const float* Wk   = (const float*)d_in[3];
  const float* bk   = (const float*)d_in[4];
  const float* Wv   = (const float*)d_in[5];
  const float* bv   = (const float*)d_in[6];
  const float* Wo   = (const float*)d_in[7];
  const float* bo   = (const float*)d_in[8];
  const float* ln1g = (const float*)d_in[9];
  const float* ln1b = (const float*)d_in[10];
  const float* W1   = (const float*)d_in[11];
  const float* b1   = (const float*)d_in[12];
  const float* W2   = (const float*)d_in[13];
  const float* b2   = (const float*)d_in[14];
  const float* ln2g = (const float*)d_in[15];
  const float* ln2b = (const float*)d_in[16];
  const float* rc   = (const float*)d_in[17];
  const float* rsn  = (const float*)d_in[18];

  char* ws = (char*)d_ws;
  const size_t MB = (size_t)1<<20;
  u16* Xbf = (u16*)(ws);             // 8MB  src bf16
  u16* Qbf = (u16*)(ws + 8*MB);      // 8MB
  u16* Kbf = (u16*)(ws + 16*MB);     // 8MB
  u16* Vbf = (u16*)(ws + 24*MB);     // 8MB
  u16* xat = (u16*)(ws + 32*MB);     // 8MB  attn context (bf16)
  u16* hbf = (u16*)(ws + 40*MB);     // 8MB  h bf16
  u16* WqT = (u16*)(ws + 48*MB);     // 2MB each
  u16* WkT = (u16*)(ws + 50*MB);
  u16* WvT = (u16*)(ws + 52*MB);
  u16* WoT = (u16*)(ws + 54*MB);
  u16* W1T = (u16*)(ws + 56*MB);     // 8MB
  u16* W2T = (u16*)(ws + 64*MB);     // 8MB
  u16* ff1 = (u16*)(ws + 72*MB);     // 32MB
  float* ao  = (float*)(ws + 104*MB); // 16MB attn_out fp32
  float* h   = (float*)(ws + 120*MB); // 16MB h fp32
  float* ff2 = (float*)(ws + 136*MB); // 16MB ff2 fp32

  dim3 blk(256);
  k_cast_bf16<<<dim3(NROWS*DIM/1024), blk, 0, stream>>>(src, Xbf, NROWS*DIM/4);
  k_transpose_cast<<<dim3(DIM/32, DIM/32), blk, 0, stream>>>(Wq, WqT, DIM, DIM);
  k_transpose_cast<<<dim3(DIM/32, DIM/32), blk, 0, stream>>>(Wk, WkT, DIM, DIM);
  k_transpose_cast<<<dim3(DIM/32, DIM/32), blk, 0, stream>>>(Wv, WvT, DIM, DIM);
  k_transpose_cast<<<dim3(DIM/32, DIM/32), blk, 0, stream>>>(Wo, WoT, DIM, DIM);
  k_transpose_cast<<<dim3(PFF/32, DIM/32), blk, 0, stream>>>(W1, W1T, DIM, PFF);
  k_transpose_cast<<<dim3(DIM/32, PFF/32), blk, 0, stream>>>(W2, W2T, PFF, DIM);

  k_gemm<false,true><<<dim3(DIM/128, NROWS/128), blk, 0, stream>>>(Xbf, WqT, bq, Qbf, NROWS, DIM, DIM);
  k_gemm<false,true><<<dim3(DIM/128, NROWS/128), blk, 0, stream>>>(Xbf, WkT, bk, Kbf, NROWS, DIM, DIM);
  k_gemm<false,true><<<dim3(DIM/128, NROWS/128), blk, 0, stream>>>(Xbf, WvT, bv, Vbf, NROWS, DIM, DIM);
  k_rope<<<dim3(NROWS*512/256), blk, 0, stream>>>(Qbf, Kbf, rc, rsn);
  k_attn<<<dim3(SEQ/64, NH, BATCH), blk, 0, stream>>>(Qbf, Kbf, Vbf, xat);
  k_gemm<false,false><<<dim3(DIM/128, NROWS/128), blk, 0, stream>>>(xat, WoT, bo, ao, NROWS, DIM, DIM);
  k_ln<true><<<dim3(NROWS), blk, 0, stream>>>(src, ao, ln1g, ln1b, h, hbf);
  k_gemm<true,true><<<dim3(PFF/128, NROWS/128), blk, 0, stream>>>(hbf, W1T, b1, ff1, NROWS, PFF, DIM);
  k_gemm<false,false><<<dim3(DIM/128, NROWS/128), blk, 0, stream>>>(ff1, W2T, b2, ff2, NROWS, DIM, PFF);
  k_ln<false><<<dim3(NROWS), blk, 0, stream>>>(h, ff2, ln2g, ln2b, (float*)d_out, nullptr);
}

// Round 3
// 349.276 us; speedup vs baseline: 1.1878x; 1.1878x over previous
//
#include <hip/hip_runtime.h>

#define SEQ 2048
#define DIM 1024
#define NH 16
#define HDIM 64
#define PFF 4096
#define NROWS 4096  // B*S
#define BATCH 2
#define NQKV 3072

typedef unsigned short u16;
typedef unsigned int u32;
typedef __attribute__((ext_vector_type(8))) short short8;
typedef __attribute__((ext_vector_type(4))) float f32x4;
typedef __attribute__((ext_vector_type(2))) unsigned int u32x2;

__device__ inline float b2f(u16 u){ return __uint_as_float(((u32)u)<<16); }
__device__ inline u16 f2b(float f){
  u32 u = __float_as_uint(f);
  u32 r = u + 0x7FFFu + ((u>>16)&1u);
  return (u16)(r>>16);
}

// C-style casts: clang allows addrspacecast via C-style cast (static_cast does not)
#define AS1C(p) ((const __attribute__((address_space(1))) unsigned int*)(p))
#define AS3P(p) ((__attribute__((address_space(3))) unsigned int*)(p))

__device__ __forceinline__ unsigned ldsOff(void* p){
  return (unsigned)(size_t)((__attribute__((address_space(3))) char*)(p));
}

// ---------------- elementwise cast fp32 -> bf16 (float4 per thread) ----------------
__global__ void k_cast_bf16(const float* __restrict__ in, u16* __restrict__ out, int n4){
  int i = blockIdx.x*256 + threadIdx.x;
  if (i >= n4) return;
  float4 v = ((const float4*)in)[i];
  ushort4 o;
  o.x = f2b(v.x); o.y = f2b(v.y); o.z = f2b(v.z); o.w = f2b(v.w);
  ((ushort4*)out)[i] = o;
}

// ---------------- transpose + cast: in fp32 [R][C] -> out bf16 [C][R] ----------------
__global__ __launch_bounds__(256) void k_transpose_cast(const float* __restrict__ in,
                                                        u16* __restrict__ out, int R, int C){
  __shared__ float tile[32][33];
  int tx = threadIdx.x & 31, ty = threadIdx.x >> 5;
  int c0 = blockIdx.x*32, r0 = blockIdx.y*32;
  #pragma unroll
  for (int i=0;i<4;++i)
    tile[ty+i*8][tx] = in[(size_t)(r0+ty+i*8)*C + c0 + tx];
  __syncthreads();
  #pragma unroll
  for (int i=0;i<4;++i)
    out[(size_t)(c0+ty+i*8)*R + r0 + tx] = f2b(tile[tx][ty+i*8]);
}

// ---------------- bf16 transpose: VT[d][r] = QKV[r][2048+d] ----------------
__global__ __launch_bounds__(256) void k_transpose_v(const u16* __restrict__ QKV, u16* __restrict__ VT){
  __shared__ u16 tile[32][34];
  int tx = threadIdx.x & 31, ty = threadIdx.x >> 5;
  int d0 = blockIdx.x*32, r0 = blockIdx.y*32;
  #pragma unroll
  for (int i=0;i<4;++i)
    tile[ty+i*8][tx] = QKV[(size_t)(r0+ty+i*8)*NQKV + 2048 + d0 + tx];
  __syncthreads();
  #pragma unroll
  for (int i=0;i<4;++i)
    VT[(size_t)(d0+ty+i*8)*NROWS + r0 + tx] = tile[tx][ty+i*8];
}

// ---------------- pack 3 bias vectors ----------------
__global__ void k_pack3(const float* __restrict__ a, const float* __restrict__ b,
                        const float* __restrict__ c, float* __restrict__ o){
  int i = blockIdx.x*256 + threadIdx.x;
  if (i >= NQKV) return;
  o[i] = i < 1024 ? a[i] : (i < 2048 ? b[i-1024] : c[i-2048]);
}

// ---------------- GEMM: C[M][N] = A[M][K](bf16) * Bt[N][K](bf16)^T + bias ----------------
// 128x128 tile, BK=64, global_load_lds staging with pre-swizzled source (m173/m97)
template<bool RELU, bool BF16OUT>
__global__ __launch_bounds__(256) void k_gemm(
    const u16* __restrict__ A, const u16* __restrict__ Bt,
    const float* __restrict__ bias, void* __restrict__ Cp,
    int M, int N, int K){
  __shared__ __align__(16) char lds[32768];
  const int tid = threadIdx.x;
  const int lane = tid & 63, wid = tid >> 6;
  const int quad = lane >> 4, l15 = lane & 15;
  const int wr = wid >> 1, wc = wid & 1;
  const int rowBase = blockIdx.y * 128, colBase = blockIdx.x * 128;
  f32x4 acc[4][4] = {};
  const int srow = lane >> 3;
  const int scol = lane & 7;
  for (int k0 = 0; k0 < K; k0 += 64) {
    __syncthreads();
    #pragma unroll
    for (int i=0;i<4;++i){
      int wch = wid*4 + i;                // wave-chunk 0..15 (8 rows each)
      int row = wch*8 + srow;             // 0..127
      int c   = scol ^ (row & 7);         // pre-swizzled source chunk
      const u16* ga = A  + (size_t)(rowBase+row)*K + k0 + c*8;
      __builtin_amdgcn_global_load_lds(AS1C(ga), AS3P(lds + wch*1024), 16, 0, 0);
      const u16* gb = Bt + (size_t)(colBase+row)*K + k0 + c*8;
      __builtin_amdgcn_global_load_lds(AS1C(gb), AS3P(lds + 16384 + wch*1024), 16, 0, 0);
    }
    __syncthreads();
    #pragma unroll
    for (int kk=0;kk<2;++kk){
      short8 af[4], bfr[4];
      #pragma unroll
      for (int m=0;m<4;++m){
        int r = wr*64 + m*16 + l15;
        af[m] = *(const short8*)(lds + ((r*128 + kk*64 + quad*16) ^ ((r&7)<<4)));
      }
      #pragma unroll
      for (int n=0;n<4;++n){
        int r = wc*64 + n*16 + l15;
        bfr[n] = *(const short8*)(lds + 16384 + ((r*128 + kk*64 + quad*16) ^ ((r&7)<<4)));
      }
      #pragma unroll
      for (int m=0;m<4;++m)
        #pragma unroll
        for (int n=0;n<4;++n)
          acc[m][n] = __builtin_amdgcn_mfma_f32_16x16x32_bf16(af[m], bfr[n], acc[m][n], 0,0,0);
    }
  }
  #pragma unroll
  for (int m=0;m<4;++m){
    #pragma unroll
    for (int n=0;n<4;++n){
      int col = colBase + wc*64 + n*16 + l15;
      float bv = bias[col];
      #pragma unroll
      for (int j=0;j<4;++j){
        int row = rowBase + wr*64 + m*16 + quad*4 + j;
        float v = acc[m][n][j] + bv;
        if (RELU) v = fmaxf(v, 0.f);
        if (BF16OUT) ((u16*)Cp)[(size_t)row*N + col] = f2b(v);
        else         ((float*)Cp)[(size_t)row*N + col] = v;
      }
    }
  }
}

// ---------------- RoPE in-place on fused QKV: Q cols scaled by 1/8, K cols ----------------
__global__ void k_rope(u16* __restrict__ QKV,
                       const float* __restrict__ cosT, const float* __restrict__ sinT){
  int idx = blockIdx.x*256 + threadIdx.x;   // NROWS*512 threads, one (q,k) pair each
  int row = idx >> 9, p = idx & 511;
  int s = row & (SEQ-1);
  float c = cosT[s*512 + p], sn = sinT[s*512 + p];
  u16* qp = QKV + (size_t)row*NQKV + 2*p;
  u16* kp = qp + 1024;
  ushort2 q = *(ushort2*)qp;
  ushort2 k = *(ushort2*)kp;
  float qx = b2f(q.x), qy = b2f(q.y), kx = b2f(k.x), ky = b2f(k.y);
  const float scale = 0.125f;   // 1/sqrt(HD)
  ushort2 qo, ko;
  qo.x = f2b((qx*c - qy*sn)*scale);
  qo.y = f2b((qx*sn + qy*c)*scale);
  ko.x = f2b(kx*c - ky*sn);
  ko.y = f2b(kx*sn + ky*c);
  *(ushort2*)qp = qo;
  *(ushort2*)kp = ko;
}

// ---------------- flash attention: q-tile 128, 8 waves, KV-tile 64 ----------------
// LDS: Qs [128][64] swz @0 (16KB) | Ks [64][64] swz @16384 (8KB)
//      Vts(V^T rows=hd) [64][64] swz @24576 (8KB) | P per-wave tr-layout @32768+wid*2048
__global__ __launch_bounds__(512) void k_attn(
    const u16* __restrict__ QKV, const u16* __restrict__ VT, u16* __restrict__ Xo){
  const int qt = blockIdx.x, h = blockIdx.y, b = blockIdx.z;
  const int tid = threadIdx.x, lane = tid & 63, wid = tid >> 6;
  const int quad = lane >> 4, l15 = lane & 15;
  __shared__ __align__(16) char lds[49152];
  const int srow = lane >> 3, scol = lane & 7;
  // ---- stage Q (once): 128 rows x 128B, 16 wave-chunks / 8 waves = 2 each
  const size_t qrow0 = (size_t)(b*SEQ + qt*128);
  #pragma unroll
  for (int i=0;i<2;++i){
    int wch = wid*2 + i;
    int row = wch*8 + srow;
    int c = scol ^ (row & 7);
    const u16* gp = QKV + (qrow0 + row)*NQKV + h*HDIM + c*8;
    __builtin_amdgcn_global_load_lds(AS1C(gp), AS3P(lds + wch*1024), 16, 0, 0);
  }
  __syncthreads();   // drains vmcnt -> Q resident
  // hoist Q fragments (loop-invariant)
  short8 qa[2];
  {
    int ar = wid*16 + l15;
    qa[0] = *(const short8*)(lds + ((ar*128 +  0 + quad*16) ^ ((ar&7)<<4)));
    qa[1] = *(const short8*)(lds + ((ar*128 + 64 + quad*16) ^ ((ar&7)<<4)));
  }
  char* PB = lds + 32768 + wid*2048;
  const unsigned pbase = ldsOff(PB);
  float m_run[4] = {-1e30f,-1e30f,-1e30f,-1e30f};
  float s_run[4] = {0.f,0.f,0.f,0.f};
  f32x4 oacc[4] = {};
  const size_t krow0 = (size_t)(b*SEQ);
  for (int kt=0; kt<SEQ/64; ++kt){
    __syncthreads();
    { // K tile: 8 wave-chunks, 1 per wave
      int row = wid*8 + srow;
      int c = scol ^ (row & 7);
      const u16* gp = QKV + (krow0 + kt*64 + row)*NQKV + 1024 + h*HDIM + c*8;
      __builtin_amdgcn_global_load_lds(AS1C(gp), AS3P(lds + 16384 + wid*1024), 16, 0, 0);
    }
    { // V^T tile: rows = hd (64), cols = k
      int row = wid*8 + srow;
      int c = scol ^ (row & 7);
      const u16* gp = VT + (size_t)(h*HDIM + row)*NROWS + b*SEQ + kt*64 + c*8;
      __builtin_amdgcn_global_load_lds(AS1C(gp), AS3P(lds + 24576 + wid*1024), 16, 0, 0);
    }
    __syncthreads();
    // ---- S = Q K^T (wave's 16 q-rows x 64 k)
    f32x4 sacc[4] = {};
    #pragma unroll
    for (int kk=0;kk<2;++kk){
      #pragma unroll
      for (int n=0;n<4;++n){
        int br = n*16 + l15;
        short8 bb = *(const short8*)(lds + 16384 + ((br*128 + kk*64 + quad*16) ^ ((br&7)<<4)));
        sacc[n] = __builtin_amdgcn_mfma_f32_16x16x32_bf16(qa[kk], bb, sacc[n], 0,0,0);
      }
    }
    // ---- online softmax (row = quad*4+j)
    float mnew[4], alpha[4], tsum[4];
    #pragma unroll
    for (int j=0;j<4;++j){
      float t = fmaxf(fmaxf(sacc[0][j], sacc[1][j]), fmaxf(sacc[2][j], sacc[3][j]));
      #pragma unroll
      for (int mm=8;mm>=1;mm>>=1) t = fmaxf(t, __shfl_xor(t, mm));
      mnew[j] = fmaxf(m_run[j], t);
      alpha[j] = __expf(m_run[j] - mnew[j]);
      tsum[j] = 0.f;
    }
    u16 pb[4][4];
    #pragma unroll
    for (int n=0;n<4;++n){
      #pragma unroll
      for (int j=0;j<4;++j){
        float p = __expf(sacc[n][j] - mnew[j]);
        tsum[j] += p;
        pb[n][j] = f2b(p);
      }
    }
    #pragma unroll
    for (int j=0;j<4;++j){
      float t = tsum[j];
      #pragma unroll
      for (int mm=8;mm>=1;mm>>=1) t += __shfl_xor(t, mm);
      s_run[j] = s_run[j]*alpha[j] + t;
      m_run[j] = mnew[j];
    }
    #pragma unroll
    for (int nb=0;nb<4;++nb){
      #pragma unroll
      for (int j=0;j<4;++j) oacc[nb][j] *= alpha[j];
    }
    // ---- write P in tr-chunk layout: elem(q,k) at e=(k>>2)*64 + (k&3)*16 + q
    // lane holds P[q=quad*4+j][k=n*16+l15]: 4 j's contiguous -> ds_write_b64
    #pragma unroll
    for (int n=0;n<4;++n){
      ushort4 pk;
      pk.x = pb[n][0]; pk.y = pb[n][1]; pk.z = pb[n][2]; pk.w = pb[n][3];
      int e = (n*4 + (l15>>2))*64 + (l15&3)*16 + quad*4;
      *(ushort4*)(PB + 2*e) = pk;
    }
    // ---- O += P V  (A-frag via ds_read_b64_tr_b16, B-frag from Vts)
    // span model: 16-lane group's slots (lane l15 at +l15*8) form one 64-elem block
    // at group base kk*1024 + quad*256; lane receives block[(l&15) + j*16].
    #pragma unroll
    for (int kk=0;kk<2;++kk){
      u32x2 t0, t1;
      unsigned paddr = pbase + kk*1024 + quad*256 + l15*8;
      asm volatile("s_waitcnt lgkmcnt(0)\n\t"
                   "ds_read_b64_tr_b16 %0, %2\n\t"
                   "ds_read_b64_tr_b16 %1, %2 offset:128\n\t"
                   "s_waitcnt lgkmcnt(0)"
                   : "=&v"(t0), "=&v"(t1) : "v"(paddr) : "memory");
      __builtin_amdgcn_sched_barrier(0);
      union { u32 w[4]; short8 s8; } pu;
      pu.w[0]=t0.x; pu.w[1]=t0.y; pu.w[2]=t1.x; pu.w[3]=t1.y;
      short8 pa = pu.s8;
      #pragma unroll
      for (int nb=0;nb<4;++nb){
        int vr = nb*16 + l15;
        short8 vb = *(const short8*)(lds + 24576 + ((vr*128 + kk*64 + quad*16) ^ ((vr&7)<<4)));
        oacc[nb] = __builtin_amdgcn_mfma_f32_16x16x32_bf16(pa, vb, oacc[nb], 0,0,0);
      }
    }
  }
  #pragma unroll
  for (int nb=0;nb<4;++nb){
    #pragma unroll
    for (int j=0;j<4;++j){
      int row = qt*128 + wid*16 + quad*4 + j;
      int col = h*HDIM + nb*16 + l15;
      float v = oacc[nb][j] / s_run[j];
      Xo[((size_t)(b*SEQ + row))*DIM + col] = f2b(v);
    }
  }
}

// ---------------- residual + layernorm (row per block), optional bf16 copy ----------------
template<bool WBF>
__global__ __launch_bounds__(256) void k_ln(
    const float* __restrict__ a, const float* __restrict__ b,
    const float* __restrict__ g, const float* __restrict__ be,
    float* __restrict__ outf, u16* __restrict__ outb){
  const int row = blockIdx.x, tid = threadIdx.x;
  __shared__ float red[8];
  float4 av = ((const float4*)(a + (size_t)row*DIM))[tid];
  float4 bv = ((const float4*)(b + (size_t)row*DIM))[tid];
  float x0 = av.x+bv.x, x1 = av.y+bv.y, x2 = av.z+bv.z, x3 = av.w+bv.w;
  float s = x0+x1+x2+x3;
  #pragma unroll
  for (int o=32;o>=1;o>>=1) s += __shfl_down(s, o);
  if ((tid&63)==0) red[tid>>6] = s;
  __syncthreads();
  float mean = (red[0]+red[1]+red[2]+red[3]) * (1.0f/DIM);
  float d0=x0-mean, d1=x1-mean, d2=x2-mean, d3=x3-mean;
  float vs = d0*d0+d1*d1+d2*d2+d3*d3;
  #pragma unroll
  for (int o=32;o>=1;o>>=1) vs += __shfl_down(vs, o);
  if ((tid&63)==0) red[4+(tid>>6)] = vs;
  __syncthreads();
  float var = (red[4]+red[5]+red[6]+red[7]) * (1.0f/DIM);
  float rs = rsqrtf(var + 1e-5f);
  float4 gv = ((const float4*)g)[tid];
  float4 bev = ((const float4*)be)[tid];
  float4 y;
  y.x = d0*rs*gv.x + bev.x;
  y.y = d1*rs*gv.y + bev.y;
  y.z = d2*rs*gv.z + bev.z;
  y.w = d3*rs*gv.w + bev.w;
  ((float4*)(outf + (size_t)row*DIM))[tid] = y;
  if (WBF){
    ushort4 o4; o4.x=f2b(y.x); o4.y=f2b(y.y); o4.z=f2b(y.z); o4.w=f2b(y.w);
    ((ushort4*)(outb + (size_t)row*DIM))[tid] = o4;
  }
}

extern "C" void kernel_launch(void* const* d_in, const int* in_sizes, int n_in,
                              void* d_out, int out_size, void* d_ws, size_t ws_size,
                              hipStream_t stream){
  (void)in_sizes; (void)n_in; (void)out_size; (void)ws_size;
  const float* src  = (const float*)d_in[0];
  const float* Wq   = (const float*)d_in[1];
  const float* bq   = (const float*)d_in[2];
  const float* Wk   = (const float*)d_in[3];
  const float* bk   = (const float*)d_in[4];
  const float* Wv   = (const float*)d_in[5];
  const float* bv   = (const float*)d_in[6];
  const float* Wo   = (const float*)d_in[7];
  const float* bo   = (const float*)d_in[8];
  const float* ln1g = (const float*)d_in[9];
  const float* ln1b = (const float*)d_in[10];
  const float* W1   = (const float*)d_in[11];
  const float* b1   = (const float*)d_in[12];
  const float* W2   = (const float*)d_in[13];
  const float* b2   = (const float*)d_in[14];
  const float* ln2g = (const float*)d_in[15];
  const float* ln2b = (const float*)d_in[16];
  const float* rc   = (const float*)d_in[17];
  const float* rsn  = (const float*)d_in[18];

  char* ws = (char*)d_ws;
  const size_t MB = (size_t)1<<20;
  u16* Xbf   = (u16*)(ws);             // 8MB   src bf16
  u16* QKV   = (u16*)(ws + 8*MB);      // 24MB  fused QKV bf16 [4096][3072]
  u16* VTb   = (u16*)(ws + 32*MB);     // 8MB   V^T bf16 [1024][4096]
  u16* xat   = (u16*)(ws + 40*MB);     // 8MB   attn context bf16
  u16* hbf   = (u16*)(ws + 48*MB);     // 8MB   h bf16
  u16* WqkvT = (u16*)(ws + 56*MB);     // 6MB   [3072][1024]
  u16* WoT   = (u16*)(ws + 62*MB);     // 2MB
  u16* W1T   = (u16*)(ws + 64*MB);     // 8MB
  u16* W2T   = (u16*)(ws + 72*MB);     // 8MB
  u16* ff1   = (u16*)(ws + 80*MB);     // 32MB
  float* ao  = (float*)(ws + 112*MB);  // 16MB attn_out fp32 (reused by ff2)
  float* h   = (float*)(ws + 128*MB);  // 16MB h fp32
  float* ff2 = ao;                     // ao dead after ln1
  float* bqkv= (float*)(ws + 144*MB);  // 12KB packed biases

  dim3 blk(256);
  k_cast_bf16<<<dim3(NROWS*DIM/1024), blk, 0, stream>>>(src, Xbf, NROWS*DIM/4);
  k_transpose_cast<<<dim3(DIM/32, DIM/32), blk, 0, stream>>>(Wq, WqkvT, DIM, DIM);
  k_transpose_cast<<<dim3(DIM/32, DIM/32), blk, 0, stream>>>(Wk, WqkvT + (size_t)1024*1024, DIM, DIM);
  k_transpose_cast<<<dim3(DIM/32, DIM/32), blk, 0, stream>>>(Wv, WqkvT + (size_t)2048*1024, DIM, DIM);
  k_transpose_cast<<<dim3(DIM/32, DIM/32), blk, 0, stream>>>(Wo, WoT, DIM, DIM);
  k_transpose_cast<<<dim3(PFF/32, DIM/32), blk, 0, stream>>>(W1, W1T, DIM, PFF);
  k_transpose_cast<<<dim3(DIM/32, PFF/32), blk, 0, stream>>>(W2, W2T, PFF, DIM);
  k_pack3<<<dim3(12), blk, 0, stream>>>(bq, bk, bv, bqkv);

  // fused QKV GEMM: [4096][1024] x [3072][1024]^T -> [4096][3072] bf16
  k_gemm<false,true><<<dim3(NQKV/128, NROWS/128), blk, 0, stream>>>(Xbf, WqkvT, bqkv, QKV, NROWS, NQKV, DIM);
  k_rope<<<dim3(NROWS*512/256), blk, 0, stream>>>(QKV, rc, rsn);
  k_transpose_v<<<dim3(DIM/32, NROWS/32), blk, 0, stream>>>(QKV, VTb);
  k_attn<<<dim3(SEQ/128, NH, BATCH), dim3(512), 0, stream>>>(QKV, VTb, xat);
  k_gemm<false,false><<<dim3(DIM/128, NROWS/128), blk, 0, stream>>>(xat, WoT, bo, ao, NROWS, DIM, DIM);
  k_ln<true><<<dim3(NROWS), blk, 0, stream>>>(src, ao, ln1g, ln1b, h, hbf);
  k_gemm<true,true><<<dim3(PFF/128, NROWS/128), blk, 0, stream>>>(hbf, W1T, b1, ff1, NROWS, PFF, DIM);
  k_gemm<false,false><<<dim3(DIM/128, NROWS/128), blk, 0, stream>>>(ff1, W2T, b2, ff2, NROWS, DIM, PFF);
  k_ln<false><<<dim3(NROWS), blk, 0, stream>>>(h, ff2, ln2g, ln2b, (float*)d_out, nullptr);
}

// Round 4
// 307.718 us; speedup vs baseline: 1.3482x; 1.1351x over previous
//
#include <hip/hip_runtime.h>

#define SEQ 2048
#define DIM 1024
#define NH 16
#define HDIM 64
#define PFF 4096
#define NROWS 4096  // B*S
#define BATCH 2
#define NQKV 3072

typedef unsigned short u16;
typedef unsigned int u32;
typedef __attribute__((ext_vector_type(8))) short short8;
typedef __attribute__((ext_vector_type(4))) float f32x4;
typedef __attribute__((ext_vector_type(16))) float f32x16;

__device__ inline float b2f(u16 u){ return __uint_as_float(((u32)u)<<16); }
__device__ inline u16 f2b(float f){
  u32 u = __float_as_uint(f);
  u32 r = u + 0x7FFFu + ((u>>16)&1u);
  return (u16)(r>>16);
}

// C-style casts: clang allows addrspacecast via C-style cast (static_cast does not)
#define AS1C(p) ((const __attribute__((address_space(1))) unsigned int*)(p))
#define AS3P(p) ((__attribute__((address_space(3))) unsigned int*)(p))

// ---------------- elementwise cast fp32 -> bf16 (float4 per thread) ----------------
__global__ void k_cast_bf16(const float* __restrict__ in, u16* __restrict__ out, int n4){
  int i = blockIdx.x*256 + threadIdx.x;
  if (i >= n4) return;
  float4 v = ((const float4*)in)[i];
  ushort4 o;
  o.x = f2b(v.x); o.y = f2b(v.y); o.z = f2b(v.z); o.w = f2b(v.w);
  ((ushort4*)out)[i] = o;
}

// ---------------- transpose + cast: in fp32 [R][C] -> out bf16 [C][R] ----------------
__global__ __launch_bounds__(256) void k_transpose_cast(const float* __restrict__ in,
                                                        u16* __restrict__ out, int R, int C){
  __shared__ float tile[32][33];
  int tx = threadIdx.x & 31, ty = threadIdx.x >> 5;
  int c0 = blockIdx.x*32, r0 = blockIdx.y*32;
  #pragma unroll
  for (int i=0;i<4;++i)
    tile[ty+i*8][tx] = in[(size_t)(r0+ty+i*8)*C + c0 + tx];
  __syncthreads();
  #pragma unroll
  for (int i=0;i<4;++i)
    out[(size_t)(c0+ty+i*8)*R + r0 + tx] = f2b(tile[tx][ty+i*8]);
}

// ---------------- bf16 transpose: VT[d][r] = QKV[r][2048+d] ----------------
__global__ __launch_bounds__(256) void k_transpose_v(const u16* __restrict__ QKV, u16* __restrict__ VT){
  __shared__ u16 tile[32][34];
  int tx = threadIdx.x & 31, ty = threadIdx.x >> 5;
  int d0 = blockIdx.x*32, r0 = blockIdx.y*32;
  #pragma unroll
  for (int i=0;i<4;++i)
    tile[ty+i*8][tx] = QKV[(size_t)(r0+ty+i*8)*NQKV + 2048 + d0 + tx];
  __syncthreads();
  #pragma unroll
  for (int i=0;i<4;++i)
    VT[(size_t)(d0+ty+i*8)*NROWS + r0 + tx] = tile[tx][ty+i*8];
}

// ---------------- pack 3 bias vectors ----------------
__global__ void k_pack3(const float* __restrict__ a, const float* __restrict__ b,
                        const float* __restrict__ c, float* __restrict__ o){
  int i = blockIdx.x*256 + threadIdx.x;
  if (i >= NQKV) return;
  o[i] = i < 1024 ? a[i] : (i < 2048 ? b[i-1024] : c[i-2048]);
}

// ---------------- GEMM: C[M][N] = A[M][K](bf16) * Bt[N][K](bf16)^T + bias ----------------
template<bool RELU, bool BF16OUT>
__global__ __launch_bounds__(256) void k_gemm(
    const u16* __restrict__ A, const u16* __restrict__ Bt,
    const float* __restrict__ bias, void* __restrict__ Cp,
    int M, int N, int K){
  __shared__ __align__(16) char lds[32768];
  const int tid = threadIdx.x;
  const int lane = tid & 63, wid = tid >> 6;
  const int quad = lane >> 4, l15 = lane & 15;
  const int wr = wid >> 1, wc = wid & 1;
  const int rowBase = blockIdx.y * 128, colBase = blockIdx.x * 128;
  f32x4 acc[4][4] = {};
  const int srow = lane >> 3;
  const int scol = lane & 7;
  for (int k0 = 0; k0 < K; k0 += 64) {
    __syncthreads();
    #pragma unroll
    for (int i=0;i<4;++i){
      int wch = wid*4 + i;                // wave-chunk 0..15 (8 rows each)
      int row = wch*8 + srow;             // 0..127
      int c   = scol ^ (row & 7);         // pre-swizzled source chunk
      const u16* ga = A  + (size_t)(rowBase+row)*K + k0 + c*8;
      __builtin_amdgcn_global_load_lds(AS1C(ga), AS3P(lds + wch*1024), 16, 0, 0);
      const u16* gb = Bt + (size_t)(colBase+row)*K + k0 + c*8;
      __builtin_amdgcn_global_load_lds(AS1C(gb), AS3P(lds + 16384 + wch*1024), 16, 0, 0);
    }
    __syncthreads();
    #pragma unroll
    for (int kk=0;kk<2;++kk){
      short8 af[4], bfr[4];
      #pragma unroll
      for (int m=0;m<4;++m){
        int r = wr*64 + m*16 + l15;
        af[m] = *(const short8*)(lds + ((r*128 + kk*64 + quad*16) ^ ((r&7)<<4)));
      }
      #pragma unroll
      for (int n=0;n<4;++n){
        int r = wc*64 + n*16 + l15;
        bfr[n] = *(const short8*)(lds + 16384 + ((r*128 + kk*64 + quad*16) ^ ((r&7)<<4)));
      }
      #pragma unroll
      for (int m=0;m<4;++m)
        #pragma unroll
        for (int n=0;n<4;++n)
          acc[m][n] = __builtin_amdgcn_mfma_f32_16x16x32_bf16(af[m], bfr[n], acc[m][n], 0,0,0);
    }
  }
  #pragma unroll
  for (int m=0;m<4;++m){
    #pragma unroll
    for (int n=0;n<4;++n){
      int col = colBase + wc*64 + n*16 + l15;
      float bv = bias[col];
      #pragma unroll
      for (int j=0;j<4;++j){
        int row = rowBase + wr*64 + m*16 + quad*4 + j;
        float v = acc[m][n][j] + bv;
        if (RELU) v = fmaxf(v, 0.f);
        if (BF16OUT) ((u16*)Cp)[(size_t)row*N + col] = f2b(v);
        else         ((float*)Cp)[(size_t)row*N + col] = v;
      }
    }
  }
}

// ---------------- RoPE in-place on fused QKV: Q cols scaled by 1/8, K cols ----------------
__global__ void k_rope(u16* __restrict__ QKV,
                       const float* __restrict__ cosT, const float* __restrict__ sinT){
  int idx = blockIdx.x*256 + threadIdx.x;   // NROWS*512 threads, one (q,k) pair each
  int row = idx >> 9, p = idx & 511;
  int s = row & (SEQ-1);
  float c = cosT[s*512 + p], sn = sinT[s*512 + p];
  u16* qp = QKV + (size_t)row*NQKV + 2*p;
  u16* kp = qp + 1024;
  ushort2 q = *(ushort2*)qp;
  ushort2 k = *(ushort2*)kp;
  float qx = b2f(q.x), qy = b2f(q.y), kx = b2f(k.x), ky = b2f(k.y);
  const float scale = 0.125f;   // 1/sqrt(HD)
  ushort2 qo, ko;
  qo.x = f2b((qx*c - qy*sn)*scale);
  qo.y = f2b((qx*sn + qy*c)*scale);
  ko.x = f2b(kx*c - ky*sn);
  ko.y = f2b(kx*sn + ky*c);
  *(ushort2*)qp = qo;
  *(ushort2*)kp = ko;
}

// ---------------- flash attention v2: swapped QK^T, in-register softmax ----------------
// 4 warps x 32 q-rows (q-tile 128), KVBLK=64, mfma_32x32x16.
// Swapped QK^T: pacc[kb][r] = S[k=32kb+crow(r,hi)][q=lane&31], crow(r,hi)=(r&3)+8*(r>>2)+4*hi.
// Lane owns q-column lane&31 (half the k's; lane^32 the other half) -> reduces are
// in-register + one shfl_xor(32). P->PV A-frag via cvt_pk_bf16 + permlane32_swap (T12).
// LDS: K[64][64] swz @0 (8KB) | Vt[64][64] swz @8192 (8KB)
__global__ __launch_bounds__(256) void k_attn(
    const u16* __restrict__ QKV, const u16* __restrict__ VT, u16* __restrict__ Xo){
  const int qt = blockIdx.x, h = blockIdx.y, b = blockIdx.z;
  const int tid = threadIdx.x, lane = tid & 63, wid = tid >> 6;
  const int l31 = lane & 31, hi = lane >> 5;
  __shared__ __align__(16) char lds[16384];
  const int srow = lane >> 3, scol = lane & 7;

  // Q -> registers: qf[dk] = Q[q=qt*128+wid*32+l31][d=dk*16+8*hi .. +7]
  short8 qf[4];
  {
    const u16* qrow = QKV + (size_t)(b*SEQ + qt*128 + wid*32 + l31)*NQKV + h*HDIM;
    #pragma unroll
    for (int dk=0; dk<4; ++dk)
      qf[dk] = *(const short8*)(qrow + dk*16 + 8*hi);
  }
  float m_run = -1e30f, s_run = 0.f;
  f32x16 oacc[2] = {};
  const size_t krow0 = (size_t)(b*SEQ);
  for (int kt=0; kt<SEQ/64; ++kt){
    __syncthreads();
    #pragma unroll
    for (int i=0;i<2;++i){
      int wch = wid*2 + i;           // 0..7 (8 rows each)
      int row = wch*8 + srow;
      int c = scol ^ (row & 7);
      const u16* gk = QKV + (krow0 + kt*64 + row)*NQKV + 1024 + h*HDIM + c*8;
      __builtin_amdgcn_global_load_lds(AS1C(gk), AS3P(lds + wch*1024), 16, 0, 0);
      const u16* gv = VT + (size_t)(h*HDIM + row)*NROWS + b*SEQ + kt*64 + c*8;
      __builtin_amdgcn_global_load_lds(AS1C(gv), AS3P(lds + 8192 + wch*1024), 16, 0, 0);
    }
    __syncthreads();
    // ---- S^T = K Q^T : pacc[kb][r] = S[32kb+crow(r,hi)][q=l31]
    f32x16 pacc[2] = {};
    #pragma unroll
    for (int kb=0;kb<2;++kb){
      #pragma unroll
      for (int dk=0;dk<4;++dk){
        int row = kb*32 + l31;
        short8 kf = *(const short8*)(lds + ((row*128 + dk*32 + 16*hi) ^ ((row&7)<<4)));
        pacc[kb] = __builtin_amdgcn_mfma_f32_32x32x16_bf16(kf, qf[dk], pacc[kb], 0,0,0);
      }
    }
    // ---- tile max for q=l31 (in-register + partner half)
    float tmax = -1e30f;
    #pragma unroll
    for (int kb=0;kb<2;++kb)
      #pragma unroll
      for (int r=0;r<16;++r) tmax = fmaxf(tmax, pacc[kb][r]);
    tmax = fmaxf(tmax, __shfl_xor(tmax, 32));
    // ---- defer-max (T13): rescale only when growth > 8
    if (__any(tmax > m_run + 8.0f)){
      float mnew = fmaxf(m_run, tmax);
      float a = __expf(m_run - mnew);
      s_run *= a;
      m_run = mnew;
      #pragma unroll
      for (int r=0;r<16;++r){
        int src = (r&3) + 8*(r>>2) + 4*hi;   // q-row of acc reg r
        float ar = __shfl(a, src);
        oacc[0][r] *= ar;
        oacc[1][r] *= ar;
      }
    }
    // ---- P = exp(S - m_run), row-sum
    float p[2][16];
    float psum = 0.f;
    #pragma unroll
    for (int kb=0;kb<2;++kb)
      #pragma unroll
      for (int r=0;r<16;++r){
        float e = __expf(pacc[kb][r] - m_run);
        p[kb][r] = e;
        psum += e;
      }
    psum += __shfl_xor(psum, 32);
    s_run += psum;
    // ---- pack P into PV A-fragments: pa[ks=2*kb+s]
    short8 pa[4];
    #pragma unroll
    for (int kb=0;kb<2;++kb){
      #pragma unroll
      for (int s=0;s<2;++s){
        u32 X0, X1, Y0, Y1;
        asm("v_cvt_pk_bf16_f32 %0, %1, %2" : "=v"(X0) : "v"(p[kb][8*s+0]), "v"(p[kb][8*s+1]));
        asm("v_cvt_pk_bf16_f32 %0, %1, %2" : "=v"(X1) : "v"(p[kb][8*s+2]), "v"(p[kb][8*s+3]));
        asm("v_cvt_pk_bf16_f32 %0, %1, %2" : "=v"(Y0) : "v"(p[kb][8*s+4]), "v"(p[kb][8*s+5]));
        asm("v_cvt_pk_bf16_f32 %0, %1, %2" : "=v"(Y1) : "v"(p[kb][8*s+6]), "v"(p[kb][8*s+7]));
        asm volatile("v_permlane32_swap_b32 %0, %1" : "+v"(X0), "+v"(Y0));
        asm volatile("v_permlane32_swap_b32 %0, %1" : "+v"(X1), "+v"(Y1));
        union { u32 w[4]; short8 s8; } pu;
        pu.w[0] = X0; pu.w[1] = X1; pu.w[2] = Y0; pu.w[3] = Y1;
        pa[2*kb+s] = pu.s8;
      }
    }
    // ---- O += P V   (B-frag from Vt[d][k] tile)
    #pragma unroll
    for (int db=0;db<2;++db){
      #pragma unroll
      for (int ks=0;ks<4;++ks){
        int row = db*32 + l31;
        short8 vf = *(const short8*)(lds + 8192 + ((row*128 + ks*32 + 16*hi) ^ ((row&7)<<4)));
        oacc[db] = __builtin_amdgcn_mfma_f32_32x32x16_bf16(pa[ks], vf, oacc[db], 0,0,0);
      }
    }
  }
  // ---- epilogue: divide by row-sum (redistribute s_run to acc rows), write out
  #pragma unroll
  for (int r=0;r<16;++r){
    int crow = (r&3) + 8*(r>>2) + 4*hi;
    float sq = __shfl(s_run, crow);
    float rs = __builtin_amdgcn_rcpf(sq);
    int grow = b*SEQ + qt*128 + wid*32 + crow;
    Xo[(size_t)grow*DIM + h*HDIM + l31]      = f2b(oacc[0][r] * rs);
    Xo[(size_t)grow*DIM + h*HDIM + 32 + l31] = f2b(oacc[1][r] * rs);
  }
}

// ---------------- residual + layernorm (row per block), optional bf16 copy ----------------
template<bool WBF>
__global__ __launch_bounds__(256) void k_ln(
    const float* __restrict__ a, const float* __restrict__ b,
    const float* __restrict__ g, const float* __restrict__ be,
    float* __restrict__ outf, u16* __restrict__ outb){
  const int row = blockIdx.x, tid = threadIdx.x;
  __shared__ float red[8];
  float4 av = ((const float4*)(a + (size_t)row*DIM))[tid];
  float4 bv = ((const float4*)(b + (size_t)row*DIM))[tid];
  float x0 = av.x+bv.x, x1 = av.y+bv.y, x2 = av.z+bv.z, x3 = av.w+bv.w;
  float s = x0+x1+x2+x3;
  #pragma unroll
  for (int o=32;o>=1;o>>=1) s += __shfl_down(s, o);
  if ((tid&63)==0) red[tid>>6] = s;
  __syncthreads();
  float mean = (red[0]+red[1]+red[2]+red[3]) * (1.0f/DIM);
  float d0=x0-mean, d1=x1-mean, d2=x2-mean, d3=x3-mean;
  float vs = d0*d0+d1*d1+d2*d2+d3*d3;
  #pragma unroll
  for (int o=32;o>=1;o>>=1) vs += __shfl_down(vs, o);
  if ((tid&63)==0) red[4+(tid>>6)] = vs;
  __syncthreads();
  float var = (red[4]+red[5]+red[6]+red[7]) * (1.0f/DIM);
  float rs = rsqrtf(var + 1e-5f);
  float4 gv = ((const float4*)g)[tid];
  float4 bev = ((const float4*)be)[tid];
  float4 y;
  y.x = d0*rs*gv.x + bev.x;
  y.y = d1*rs*gv.y + bev.y;
  y.z = d2*rs*gv.z + bev.z;
  y.w = d3*rs*gv.w + bev.w;
  ((float4*)(outf + (size_t)row*DIM))[tid] = y;
  if (WBF){
    ushort4 o4; o4.x=f2b(y.x); o4.y=f2b(y.y); o4.z=f2b(y.z); o4.w=f2b(y.w);
    ((ushort4*)(outb + (size_t)row*DIM))[tid] = o4;
  }
}

extern "C" void kernel_launch(void* const* d_in, const int* in_sizes, int n_in,
                              void* d_out, int out_size, void* d_ws, size_t ws_size,
                              hipStream_t stream){
  (void)in_sizes; (void)n_in; (void)out_size; (void)ws_size;
  const float* src  = (const float*)d_in[0];
  const float* Wq   = (const float*)d_in[1];
  const float* bq   = (const float*)d_in[2];
  const float* Wk   = (const float*)d_in[3];
  const float* bk   = (const float*)d_in[4];
  const float* Wv   = (const float*)d_in[5];
  const float* bv   = (const float*)d_in[6];
  const float* Wo   = (const float*)d_in[7];
  const float* bo   = (const float*)d_in[8];
  const float* ln1g = (const float*)d_in[9];
  const float* ln1b = (const float*)d_in[10];
  const float* W1   = (const float*)d_in[11];
  const float* b1   = (const float*)d_in[12];
  const float* W2   = (const float*)d_in[13];
  const float* b2   = (const float*)d_in[14];
  const float* ln2g = (const float*)d_in[15];
  const float* ln2b = (const float*)d_in[16];
  const float* rc   = (const float*)d_in[17];
  const float* rsn  = (const float*)d_in[18];

  char* ws = (char*)d_ws;
  const size_t MB = (size_t)1<<20;
  u16* Xbf   = (u16*)(ws);             // 8MB   src bf16
  u16* QKV   = (u16*)(ws + 8*MB);      // 24MB  fused QKV bf16 [4096][3072]
  u16* VTb   = (u16*)(ws + 32*MB);     // 8MB   V^T bf16 [1024][4096]
  u16* xat   = (u16*)(ws + 40*MB);     // 8MB   attn context bf16
  u16* hbf   = (u16*)(ws + 48*MB);     // 8MB   h bf16
  u16* WqkvT = (u16*)(ws + 56*MB);     // 6MB   [3072][1024]
  u16* WoT   = (u16*)(ws + 62*MB);     // 2MB
  u16* W1T   = (u16*)(ws + 64*MB);     // 8MB
  u16* W2T   = (u16*)(ws + 72*MB);     // 8MB
  u16* ff1   = (u16*)(ws + 80*MB);     // 32MB
  float* ao  = (float*)(ws + 112*MB);  // 16MB attn_out fp32 (reused by ff2)
  float* h   = (float*)(ws + 128*MB);  // 16MB h fp32
  float* ff2 = ao;                     // ao dead after ln1
  float* bqkv= (float*)(ws + 144*MB);  // 12KB packed biases

  dim3 blk(256);
  k_cast_bf16<<<dim3(NROWS*DIM/1024), blk, 0, stream>>>(src, Xbf, NROWS*DIM/4);
  k_transpose_cast<<<dim3(DIM/32, DIM/32), blk, 0, stream>>>(Wq, WqkvT, DIM, DIM);
  k_transpose_cast<<<dim3(DIM/32, DIM/32), blk, 0, stream>>>(Wk, WqkvT + (size_t)1024*1024, DIM, DIM);
  k_transpose_cast<<<dim3(DIM/32, DIM/32), blk, 0, stream>>>(Wv, WqkvT + (size_t)2048*1024, DIM, DIM);
  k_transpose_cast<<<dim3(DIM/32, DIM/32), blk, 0, stream>>>(Wo, WoT, DIM, DIM);
  k_transpose_cast<<<dim3(PFF/32, DIM/32), blk, 0, stream>>>(W1, W1T, DIM, PFF);
  k_transpose_cast<<<dim3(DIM/32, PFF/32), blk, 0, stream>>>(W2, W2T, PFF, DIM);
  k_pack3<<<dim3(12), blk, 0, stream>>>(bq, bk, bv, bqkv);

  // fused QKV GEMM: [4096][1024] x [3072][1024]^T -> [4096][3072] bf16
  k_gemm<false,true><<<dim3(NQKV/128, NROWS/128), blk, 0, stream>>>(Xbf, WqkvT, bqkv, QKV, NROWS, NQKV, DIM);
  k_rope<<<dim3(NROWS*512/256), blk, 0, stream>>>(QKV, rc, rsn);
  k_transpose_v<<<dim3(DIM/32, NROWS/32), blk, 0, stream>>>(QKV, VTb);
  k_attn<<<dim3(SEQ/128, NH, BATCH), blk, 0, stream>>>(QKV, VTb, xat);
  k_gemm<false,false><<<dim3(DIM/128, NROWS/128), blk, 0, stream>>>(xat, WoT, bo, ao, NROWS, DIM, DIM);
  k_ln<true><<<dim3(NROWS), blk, 0, stream>>>(src, ao, ln1g, ln1b, h, hbf);
  k_gemm<true,true><<<dim3(PFF/128, NROWS/128), blk, 0, stream>>>(hbf, W1T, b1, ff1, NROWS, PFF, DIM);
  k_gemm<false,false><<<dim3(DIM/128, NROWS/128), blk, 0, stream>>>(ff1, W2T, b2, ff2, NROWS, DIM, PFF);
  k_ln<false><<<dim3(NROWS), blk, 0, stream>>>(h, ff2, ln2g, ln2b, (float*)d_out, nullptr);
}